// Round 7
// baseline (353.567 us; speedup 1.0000x reference)
//
#include <hip/hip_runtime.h>
#include <math.h>

#define N 512
#define H 128
#define L 4
#define NUM_RBF 50
#define NMOL 16
#define SUPER 64          // neighbor slots per super-tile
#define MAXS 8            // max super-tiles per node (ceil(511/64))

typedef __attribute__((ext_vector_type(8))) short short8;
typedef __attribute__((ext_vector_type(4))) float float4v;
typedef __attribute__((ext_vector_type(4))) int int4v;

// silu via v_rcp (1 ulp) instead of exact-div expansion (~8 instr, 2 trans-rate)
__device__ __forceinline__ float silu_f(float v) {
    return v * __builtin_amdgcn_rcpf(1.0f + __expf(-v));
}

__device__ __forceinline__ unsigned short f2bf(float f) {
    unsigned int u = __float_as_uint(f);
    unsigned int r = (u + 0x7FFFu + ((u >> 16) & 1u)) >> 16;  // RNE
    return (unsigned short)r;
}

// async 16B global->LDS copy. dst must be WAVE-UNIFORM; HW adds lane*16.
__device__ __forceinline__ void gld_lds16(const void* g, void* l) {
    __builtin_amdgcn_global_load_lds(
        (const __attribute__((address_space(1))) unsigned int*)g,
        (__attribute__((address_space(3))) unsigned int*)l, 16, 0, 0);
}

// Per block j (512 threads):
//  - ballot-compact valid neighbors (d<5, i!=j) into nbr[j*512..], pad to x64 with j
//  - x[j,h] = embed row;  a[j,h] = b1[h] + x[j,:] @ Wx[:,h]  (4-way split-K)
//  - precompute layer-invariant bf16 feature tiles F (rbf+dirs, 53->64 padded)
//    per (j, supertile): 64 rows x 64 shorts, 16B-chunk XOR swizzle c^(r&7)
//    (linear LDS dest for global_load_lds + conflict-floor ds_read_b128).
//    R6 lesson: Fg (32MB) is NOT cache-resident; k_layer must PREFETCH it via
//    global_load_lds (decoupled DMA), not demand-load it (274 GB/s, 52us).
//  - blocks j<L pack layer j's Wfeat into fragment-linear bf16 (Wpack,
//    16KB/layer) so k_layer's bfrag is 4 coalesced dwordx4 loads.
//  - block 0 zeroes the done-counter used by the last-layer pool fold.
__global__ __launch_bounds__(512) void k_embed_lin(const int* __restrict__ an,
                                                   const float* __restrict__ embed,
                                                   const float* __restrict__ pos,
                                                   const float* __restrict__ msg_w1,
                                                   const float* __restrict__ b1,
                                                   float* __restrict__ x,
                                                   float* __restrict__ a,
                                                   int* __restrict__ nbr,
                                                   int* __restrict__ ncnt,
                                                   unsigned short* __restrict__ Fg,
                                                   unsigned short* __restrict__ Wpack,
                                                   int* __restrict__ done_g) {
    int j = blockIdx.x;
    int tid = threadIdx.x;
    int lane = tid & 63;
    int wave = tid >> 6;
    int h = tid & 127;
    int grp = tid >> 7;

    __shared__ float xs[H];
    __shared__ int wsum8[8];
    __shared__ float part[4][H];

    float pjx = pos[j * 3 + 0], pjy = pos[j * 3 + 1], pjz = pos[j * 3 + 2];

    if (j == 0 && tid == 0) *done_g = 0;   // re-arm pool ticket each iteration

    if (tid < H) {
        int z = an[j];
        z = min(max(z, 0), 99);
        float xv = embed[z * H + tid];
        xs[tid] = xv;
        x[j * H + tid] = xv;
    }

    int padded;
    {
        int i = tid;
        float dx = pos[i * 3 + 0] - pjx;
        float dy = pos[i * 3 + 1] - pjy;
        float dz = pos[i * 3 + 2] - pjz;
        float d2 = dx * dx + dy * dy + dz * dz;
        int valid = (d2 < 25.0f) && (i != j);
        unsigned long long m = __ballot(valid);
        int pre = __popcll(m & ((1ull << lane) - 1ull));
        if (lane == 0) wsum8[wave] = __popcll(m);
        __syncthreads();
        int wbase = 0, total = 0;
        for (int w = 0; w < 8; w++) {
            if (w < wave) wbase += wsum8[w];
            total += wsum8[w];
        }
        if (valid) nbr[j * 512 + wbase + pre] = i;
        padded = (total + 63) & ~63;
        for (int s = total + tid; s < padded; s += 512) nbr[j * 512 + s] = j;
        if (tid == 0) ncnt[j] = total;
    }

    // a = b1 + xs @ Wx, 4-way split-K (Wx = first H rows of layer-0 msg_w1)
    {
        float p0 = 0.f, p1 = 0.f, p2 = 0.f, p3 = 0.f;
        int k0 = grp * 32;
#pragma unroll 8
        for (int k = 0; k < 32; k += 4) {
            p0 += xs[k0 + k]     * msg_w1[(k0 + k)     * H + h];
            p1 += xs[k0 + k + 1] * msg_w1[(k0 + k + 1) * H + h];
            p2 += xs[k0 + k + 2] * msg_w1[(k0 + k + 2) * H + h];
            p3 += xs[k0 + k + 3] * msg_w1[(k0 + k + 3) * H + h];
        }
        part[grp][h] = (p0 + p1) + (p2 + p3);
    }
    __syncthreads();   // part ready; nbr writes visible block-wide
    if (grp == 0)
        a[j * H + h] = part[0][h] + part[1][h] + part[2][h] + part[3][h] + b1[h];

    // ---- F feature precompute: 4 threads per slot, 16 features each ----
    const float DELTA = 5.0f / 49.0f;
    int kb = (tid & 3) * 16;
#pragma unroll
    for (int pass = 0; pass < 4; pass++) {
        int slot = pass * 128 + (tid >> 2);
        if (slot < padded) {
            int ni = nbr[j * 512 + slot];
            float dx = pos[ni * 3 + 0] - pjx;
            float dy = pos[ni * 3 + 1] - pjy;
            float dz = pos[ni * 3 + 2] - pjz;
            float d = sqrtf(dx * dx + dy * dy + dz * dz);
            float rinv = 1.0f / fmaxf(d, 1e-8f);
            unsigned short vals[16];
#pragma unroll
            for (int qq = 0; qq < 16; qq++) {
                int k = kb + qq;
                float v;
                if (k < NUM_RBF) {
                    float tt = d - (float)k * DELTA;
                    v = __expf(-50.0f * tt * tt);      // 1/(2*0.1^2) = 50
                } else if (k == NUM_RBF)     v = dx * rinv;
                else if (k == NUM_RBF + 1)   v = dy * rinv;
                else if (k == NUM_RBF + 2)   v = dz * rinv;
                else                         v = 0.0f;
                vals[qq] = f2bf(v);
            }
            int row = slot & 63;
            unsigned short* tile = Fg + (((size_t)(j * MAXS + (slot >> 6))) << 12);
            int c0 = kb >> 3;          // 16B-chunk index (8 shorts per chunk)
            int4v p0, p1;
#pragma unroll
            for (int q = 0; q < 4; q++) {
                p0[q] = (int)((unsigned)vals[2 * q]     | ((unsigned)vals[2 * q + 1] << 16));
                p1[q] = (int)((unsigned)vals[8 + 2 * q] | ((unsigned)vals[9 + 2 * q] << 16));
            }
            *(int4v*)(tile + row * 64 + (((c0    ) ^ (row & 7)) << 3)) = p0;
            *(int4v*)(tile + row * 64 + (((c0 + 1) ^ (row & 7)) << 3)) = p1;
        }
    }

    // ---- Wpack: block j<L packs layer j's Wfeat fragments (16KB bf16) ----
    if (j < L) {
        const float* wf = msg_w1 + j * (H + NUM_RBF + 3) * H + H * H;
        unsigned short* wl = Wpack + j * 8192;
        int wv4w = tid >> 7;
        int rem = tid & 127;
        int ln = rem >> 1;          // lane 0..63
        int c = rem & 1;
        int qd = ln >> 4, nnw = ln & 15;
#pragma unroll
        for (int t = 0; t < 2; t++) {
            int hh = wv4w * 32 + t * 16 + nnw;
            int4v pk;
#pragma unroll
            for (int q = 0; q < 4; q++) {
                int k0 = c * 32 + qd * 8 + 2 * q;
                float v0 = (k0     < NUM_RBF + 3) ? wf[(k0)     * H + hh] : 0.0f;
                float v1 = (k0 + 1 < NUM_RBF + 3) ? wf[(k0 + 1) * H + hh] : 0.0f;
                pk[q] = (int)((unsigned)f2bf(v0) | ((unsigned)f2bf(v1) << 16));
            }
            *(int4v*)(wl + ((wv4w * 64 + ln) * 4 + c * 2 + t) * 8) = pk;
        }
    }
}

// Fused per-layer kernel (R4 staged structure + Wpack bfrag + pool fold).
// Block b processes node j = order[rank], rank = b<256 ? b : 767-b (cnt-sorted
// order; blocks b and b+256 co-reside on one CU [m09] -> per-CU work ~const).
// F tiles double-buffered per wave-group, prefetched via global_load_lds.
// For the last layer (a_next==nullptr): last-arriving block (device-scope
// atomic ticket) performs the mean-pool + output MLP, deleting one dispatch.
__global__ __launch_bounds__(512) void k_layer(const float* __restrict__ a,
                                               const int* __restrict__ nbr,
                                               const int* __restrict__ ncnt,
                                               const unsigned short* __restrict__ Fg,
                                               const unsigned short* __restrict__ wpack,
                                               const float* __restrict__ w2,
                                               const float* __restrict__ b2,
                                               const float* __restrict__ u1,
                                               const float* __restrict__ ub1,
                                               const float* __restrict__ u2,
                                               const float* __restrict__ ub2,
                                               float* __restrict__ x,
                                               const float* __restrict__ wxn,
                                               const float* __restrict__ b1n,
                                               float* __restrict__ a_next,
                                               const int* __restrict__ order_in,
                                               int* __restrict__ order_out,
                                               const int* __restrict__ batch,
                                               const float* __restrict__ ow1,
                                               const float* __restrict__ ob1,
                                               const float* __restrict__ ow2,
                                               const float* __restrict__ ob2,
                                               float* __restrict__ out,
                                               int* __restrict__ done_g) {
    int b = blockIdx.x;
    int tid = threadIdx.x;
    int g = tid >> 8;          // wave-group 0..1
    int lane = tid & 63;
    int wv4 = (tid >> 6) & 3;  // wave within group
    int nn = lane & 15;
    int quad = lane >> 4;
    int hbase = wv4 * 32;

    __shared__ __align__(16) unsigned short F[2][2][SUPER * 64];  // [group][buf]
    __shared__ __align__(16) int nidx_all[512];
    __shared__ __align__(16) int cnts_l[512];
    __shared__ int order_l[512];
    __shared__ float sjp[2][H];
    __shared__ float sj[H], xj[H], ag[H], hid[H], xn[H];
    __shared__ float part[4][H];
    __shared__ int mlo[4], mhi[4];
    __shared__ float phid[4][H / 2];
    __shared__ int lastflag;

    int rank = (b < 256) ? b : 767 - b;   // pair (b, b+256) -> ranks summing 511
    int j;
    if (order_in != nullptr) {
        j = order_in[rank];
    } else {
        cnts_l[tid] = ncnt[tid];
        __syncthreads();
        int c_t = cnts_l[tid];
        int r = 0;
#pragma unroll 4
        for (int i = 0; i < 512; i += 4) {
            int4v c4 = *(const int4v*)&cnts_l[i];
            r += (c4[0] < c_t || (c4[0] == c_t && (i    ) < tid)) ? 1 : 0;
            r += (c4[1] < c_t || (c4[1] == c_t && (i + 1) < tid)) ? 1 : 0;
            r += (c4[2] < c_t || (c4[2] == c_t && (i + 2) < tid)) ? 1 : 0;
            r += (c4[3] < c_t || (c4[3] == c_t && (i + 3) < tid)) ? 1 : 0;
        }
        order_l[r] = tid;      // strict total order -> bijection
        __syncthreads();
        j = order_l[rank];
        if (order_out != nullptr && b == 0) order_out[tid] = order_l[tid];
    }

    int cnt = ncnt[j];

    if (tid < H) xj[tid] = x[j * H + tid];
    nidx_all[tid] = nbr[j * 512 + tid];   // all 512 slots, once

    // bfrag: 4 coalesced dwordx4 from Wpack (fragment-linear)
    short8 bfrag[2][2];
    {
        const unsigned short* wp = wpack + (wv4 * 64 + lane) * 32;
        bfrag[0][0] = *(const short8*)(wp);
        bfrag[0][1] = *(const short8*)(wp + 8);
        bfrag[1][0] = *(const short8*)(wp + 16);
        bfrag[1][1] = *(const short8*)(wp + 24);
    }

    int S = (cnt + 63) >> 6;
    int rounds = (S + 1) >> 1;

    // stage one 8KB F tile (64x64 shorts) into F[g][buf] via 8 async 1KB copies
    auto stage_tile = [&](int s, int buf) {
        const char* src = (const char*)(Fg + (((size_t)(j * MAXS + s)) << 12));
        char* dst = (char*)&F[g][buf][0];
#pragma unroll
        for (int q = 0; q < 2; q++) {
            int off = (wv4 + 4 * q) << 10;           // wave-uniform
            gld_lds16(src + off + lane * 16, dst + off);
        }
    };

    // prologue: stage s = g into buf 0
    if (g < S) stage_tile(g, 0);
    __syncthreads();   // drains vmcnt -> buf 0 ready, nidx_all ready

    float pacc0 = 0.0f, pacc1 = 0.0f;

    for (int r = 0; r < rounds; r++) {
        int s = 2 * r + g;
        int sn = 2 * (r + 1) + g;
        if (sn < S) stage_tile(sn, (r + 1) & 1);   // async, in flight under compute
        if (s < S) {
            int cur = r & 1;
#pragma unroll
            for (int it = 0; it < SUPER / 16; it++) {
                int lbase = it * 16 + quad * 4;
                int4v ni4 = *(const int4v*)&nidx_all[s * 64 + lbase];
                float av0[4], av1[4];
#pragma unroll
                for (int rr = 0; rr < 4; rr++) {
                    av0[rr] = a[ni4[rr] * H + hbase + nn];
                    av1[rr] = a[ni4[rr] * H + hbase + 16 + nn];
                }
                int row = it * 16 + nn;
                const char* fb = (const char*)&F[g][cur][0] + row * 128;
                short8 afrag0 = *(const short8*)(fb + ((quad       ^ (row & 7)) << 4));
                short8 afrag1 = *(const short8*)(fb + (((quad + 4) ^ (row & 7)) << 4));
                float4v acc0 = {0.0f, 0.0f, 0.0f, 0.0f};
                float4v acc1 = {0.0f, 0.0f, 0.0f, 0.0f};
                acc0 = __builtin_amdgcn_mfma_f32_16x16x32_bf16(afrag0, bfrag[0][0], acc0, 0, 0, 0);
                acc0 = __builtin_amdgcn_mfma_f32_16x16x32_bf16(afrag1, bfrag[1][0], acc0, 0, 0, 0);
                acc1 = __builtin_amdgcn_mfma_f32_16x16x32_bf16(afrag0, bfrag[0][1], acc1, 0, 0, 0);
                acc1 = __builtin_amdgcn_mfma_f32_16x16x32_bf16(afrag1, bfrag[1][1], acc1, 0, 0, 0);
#pragma unroll
                for (int rr = 0; rr < 4; rr++) {
                    float vm = (s * 64 + lbase + rr < cnt) ? 1.0f : 0.0f;
                    pacc0 += vm * silu_f(acc0[rr] + av0[rr]);
                    pacc1 += vm * silu_f(acc1[rr] + av1[rr]);
                }
            }
        }
        __syncthreads();   // one barrier per round (also drains staged loads)
    }

    // group partial -> LDS (quad shuffle-reduce; lanes 0..15 of each wave write)
    pacc0 += __shfl_xor(pacc0, 16, 64);
    pacc0 += __shfl_xor(pacc0, 32, 64);
    pacc1 += __shfl_xor(pacc1, 16, 64);
    pacc1 += __shfl_xor(pacc1, 32, 64);
    if (lane < 16) {
        sjp[g][hbase + lane]      = pacc0;
        sjp[g][hbase + 16 + lane] = pacc1;
    }
    __syncthreads();
    if (tid < H) sj[tid] = sjp[0][tid] + sjp[1][tid];
    __syncthreads();

    // ---- inline update: 4-way split-K MLP on 512 threads ----
    int h = tid & 127;
    int grp = tid >> 7;   // 0..3

    {
        float p0 = 0.f, p1 = 0.f, p2 = 0.f, p3 = 0.f;
        int k0 = grp * 32;
#pragma unroll 8
        for (int k = 0; k < 32; k += 4) {
            p0 += sj[k0 + k]     * w2[(k0 + k)     * H + h];
            p1 += sj[k0 + k + 1] * w2[(k0 + k + 1) * H + h];
            p2 += sj[k0 + k + 2] * w2[(k0 + k + 2) * H + h];
            p3 += sj[k0 + k + 3] * w2[(k0 + k + 3) * H + h];
        }
        part[grp][h] = (p0 + p1) + (p2 + p3);
    }
    __syncthreads();
    if (grp == 0) ag[h] = part[0][h] + part[1][h] + part[2][h] + part[3][h] + (float)cnt * b2[h];
    __syncthreads();

    {
        const float* src = (grp < 2) ? xj : ag;
        int sbase = (grp & 1) * 64;
        int k0 = grp * 64;
        float p0 = 0.f, p1 = 0.f, p2 = 0.f, p3 = 0.f;
#pragma unroll 8
        for (int k = 0; k < 64; k += 4) {
            p0 += src[sbase + k]     * u1[(k0 + k)     * H + h];
            p1 += src[sbase + k + 1] * u1[(k0 + k + 1) * H + h];
            p2 += src[sbase + k + 2] * u1[(k0 + k + 2) * H + h];
            p3 += src[sbase + k + 3] * u1[(k0 + k + 3) * H + h];
        }
        part[grp][h] = (p0 + p1) + (p2 + p3);
    }
    __syncthreads();
    if (grp == 0) hid[h] = silu_f(part[0][h] + part[1][h] + part[2][h] + part[3][h] + ub1[h]);
    __syncthreads();

    {
        float p0 = 0.f, p1 = 0.f, p2 = 0.f, p3 = 0.f;
        int k0 = grp * 32;
#pragma unroll 8
        for (int k = 0; k < 32; k += 4) {
            p0 += hid[k0 + k]     * u2[(k0 + k)     * H + h];
            p1 += hid[k0 + k + 1] * u2[(k0 + k + 1) * H + h];
            p2 += hid[k0 + k + 2] * u2[(k0 + k + 2) * H + h];
            p3 += hid[k0 + k + 3] * u2[(k0 + k + 3) * H + h];
        }
        part[grp][h] = (p0 + p1) + (p2 + p3);
    }
    __syncthreads();
    if (grp == 0) {
        float xv = xj[h] + part[0][h] + part[1][h] + part[2][h] + part[3][h] + ub2[h];
        x[j * H + h] = xv;
        xn[h] = xv;
    }

    if (a_next != nullptr) {
        __syncthreads();
        float p0 = 0.f, p1 = 0.f, p2 = 0.f, p3 = 0.f;
        int k0 = grp * 32;
#pragma unroll 8
        for (int k = 0; k < 32; k += 4) {
            p0 += xn[k0 + k]     * wxn[(k0 + k)     * H + h];
            p1 += xn[k0 + k + 1] * wxn[(k0 + k + 1) * H + h];
            p2 += xn[k0 + k + 2] * wxn[(k0 + k + 2) * H + h];
            p3 += xn[k0 + k + 3] * wxn[(k0 + k + 3) * H + h];
        }
        part[grp][h] = (p0 + p1) + (p2 + p3);
        __syncthreads();
        if (grp == 0)
            a_next[j * H + h] = part[0][h] + part[1][h] + part[2][h] + part[3][h] + b1n[h];
        return;
    }

    // ---- last layer: fold pool+output MLP into the last-arriving block ----
    __syncthreads();       // x[j,:] store issued by grp0 before the fence
    __threadfence();       // release this block's x writes (device scope)
    if (tid == 0) lastflag = (atomicAdd(done_g, 1) == N - 1);
    __syncthreads();
    if (!lastflag) return;
    __threadfence();       // acquire: other blocks' x writes now visible

    // 4 groups x 128 threads; group handles molecules m = grp, grp+4, grp+8, grp+12
    for (int m = grp; m < NMOL; m += 4) {
        if (h == 0) {
            int a_ = 0, b_ = N;
            while (a_ < b_) { int mid = (a_ + b_) >> 1; if (batch[mid] < m) a_ = mid + 1; else b_ = mid; }
            mlo[grp] = a_;
            b_ = N;
            while (a_ < b_) { int mid = (a_ + b_) >> 1; if (batch[mid] < m + 1) a_ = mid + 1; else b_ = mid; }
            mhi[grp] = a_;
        }
        __syncthreads();
        int lo = mlo[grp], hi = mhi[grp];
        float s = 0.0f;
        for (int i = lo; i < hi; i++) s += x[i * H + h];
        part[grp][h] = s / (float)max(hi - lo, 1);
        __syncthreads();
        if (h < H / 2) {
            float p0 = 0.f, p1 = 0.f;
            for (int k = 0; k < H; k += 2) {
                p0 += part[grp][k]     * ow1[(k)     * (H / 2) + h];
                p1 += part[grp][k + 1] * ow1[(k + 1) * (H / 2) + h];
            }
            phid[grp][h] = silu_f(p0 + p1 + ob1[h]);
        }
        __syncthreads();
        if (h == 0) {
            float o = ob2[0];
            for (int k = 0; k < H / 2; k++) o += phid[grp][k] * ow2[k];
            out[m] = o;
        }
        __syncthreads();   // mlo/part reuse next iteration
    }
}

extern "C" void kernel_launch(void* const* d_in, const int* in_sizes, int n_in,
                              void* d_out, int out_size, void* d_ws, size_t ws_size,
                              hipStream_t stream) {
    const int*   an      = (const int*)d_in[0];
    const float* pos     = (const float*)d_in[1];
    const int*   batch   = (const int*)d_in[2];
    const float* embed   = (const float*)d_in[3];
    const float* msg_w1  = (const float*)d_in[4];   // L x 181 x 128
    const float* msg_b1  = (const float*)d_in[5];
    const float* msg_w2  = (const float*)d_in[6];   // L x 128 x 128
    const float* msg_b2  = (const float*)d_in[7];
    const float* upd_w1  = (const float*)d_in[8];   // L x 256 x 128
    const float* upd_b1  = (const float*)d_in[9];
    const float* upd_w2  = (const float*)d_in[10];  // L x 128 x 128
    const float* upd_b2  = (const float*)d_in[11];
    const float* out_w1  = (const float*)d_in[12];  // 128 x 64
    const float* out_b1  = (const float*)d_in[13];
    const float* out_w2  = (const float*)d_in[14];  // 64 x 1
    const float* out_b2  = (const float*)d_in[15];
    float* out = (float*)d_out;

    float* x    = (float*)d_ws;                          // N*H
    float* a0   = x + N * H;                             // N*H (even layers)
    float* a1   = a0 + N * H;                            // N*H (odd layers)
    int*   nbr  = (int*)(a1 + N * H);                    // N*512
    int*   ncnt = nbr + N * 512;                         // N
    int*   order_g = ncnt + N;                           // N (cnt-sorted node order)
    int*   done_g  = order_g + N;                        // 4 ints (pool ticket)
    unsigned short* Wpack = (unsigned short*)(done_g + 4);  // L*8192 shorts (64 KB)
    unsigned short* Fg = Wpack + L * 8192;               // N*MAXS*4096 shorts (32 MB)

    const int W1ROWS = H + NUM_RBF + 3;  // 181

    k_embed_lin<<<N, 512, 0, stream>>>(an, embed, pos, msg_w1, msg_b1, x, a0,
                                       nbr, ncnt, Fg, Wpack, done_g);
    for (int l = 0; l < L; l++) {
        float* a_cur  = (l & 1) ? a1 : a0;
        float* a_next = (l + 1 < L) ? ((l & 1) ? a0 : a1) : nullptr;
        const float* wxn = (l + 1 < L) ? (msg_w1 + (l + 1) * W1ROWS * H) : nullptr;
        const float* b1n = (l + 1 < L) ? (msg_b1 + (l + 1) * H) : nullptr;
        const int* oin  = (l == 0) ? nullptr : order_g;
        int*       oout = (l == 0) ? order_g : nullptr;
        k_layer<<<N, 512, 0, stream>>>(a_cur, nbr, ncnt, Fg, Wpack + l * 8192,
                                       msg_w2 + l * H * H, msg_b2 + l * H,
                                       upd_w1 + l * 2 * H * H, upd_b1 + l * H,
                                       upd_w2 + l * H * H, upd_b2 + l * H,
                                       x, wxn, b1n, a_next, oin, oout,
                                       batch, out_w1, out_b1, out_w2, out_b2,
                                       out, done_g);
    }
}

// Round 8
// 199.540 us; speedup vs baseline: 1.7719x; 1.7719x over previous
//
#include <hip/hip_runtime.h>
#include <math.h>

#define N 512
#define H 128
#define L 4
#define NUM_RBF 50
#define NMOL 16
#define SUPER 64          // neighbor slots per super-tile
#define MAXS 8            // max super-tiles per node (ceil(511/64))

typedef __attribute__((ext_vector_type(8))) short short8;
typedef __attribute__((ext_vector_type(4))) float float4v;
typedef __attribute__((ext_vector_type(4))) int int4v;

// silu via v_rcp (1 ulp) instead of exact-div expansion (~8 instr, 2 trans-rate)
__device__ __forceinline__ float silu_f(float v) {
    return v * __builtin_amdgcn_rcpf(1.0f + __expf(-v));
}

__device__ __forceinline__ unsigned short f2bf(float f) {
    unsigned int u = __float_as_uint(f);
    unsigned int r = (u + 0x7FFFu + ((u >> 16) & 1u)) >> 16;  // RNE
    return (unsigned short)r;
}

// async 16B global->LDS copy. dst must be WAVE-UNIFORM; HW adds lane*16.
__device__ __forceinline__ void gld_lds16(const void* g, void* l) {
    __builtin_amdgcn_global_load_lds(
        (const __attribute__((address_space(1))) unsigned int*)g,
        (__attribute__((address_space(3))) unsigned int*)l, 16, 0, 0);
}

// Per block j (512 threads):
//  - ballot-compact valid neighbors (d<5, i!=j) into nbr[j*512..], pad to x64 with j
//  - x[j,h] = embed row;  a[j,h] = b1[h] + x[j,:] @ Wx[:,h]  (4-way split-K)
//  - precompute layer-invariant bf16 feature tiles F (rbf+dirs, 53->64 padded)
//    per (j, supertile): 64 rows x 64 shorts, 16B-chunk XOR swizzle c^(r&7)
//    (linear LDS dest for global_load_lds + conflict-floor ds_read_b128).
//    R6 lesson: Fg (32MB) is NOT cache-resident; k_layer must PREFETCH it via
//    global_load_lds (decoupled DMA), not demand-load it (274 GB/s, 52us).
//  - blocks j<L pack layer j's Wfeat into fragment-linear bf16 (Wpack,
//    16KB/layer) so k_layer's bfrag is 4 coalesced dwordx4 loads.
__global__ __launch_bounds__(512) void k_embed_lin(const int* __restrict__ an,
                                                   const float* __restrict__ embed,
                                                   const float* __restrict__ pos,
                                                   const float* __restrict__ msg_w1,
                                                   const float* __restrict__ b1,
                                                   float* __restrict__ x,
                                                   float* __restrict__ a,
                                                   int* __restrict__ nbr,
                                                   int* __restrict__ ncnt,
                                                   unsigned short* __restrict__ Fg,
                                                   unsigned short* __restrict__ Wpack) {
    int j = blockIdx.x;
    int tid = threadIdx.x;
    int lane = tid & 63;
    int wave = tid >> 6;
    int h = tid & 127;
    int grp = tid >> 7;

    __shared__ float xs[H];
    __shared__ int wsum8[8];
    __shared__ float part[4][H];

    float pjx = pos[j * 3 + 0], pjy = pos[j * 3 + 1], pjz = pos[j * 3 + 2];

    if (tid < H) {
        int z = an[j];
        z = min(max(z, 0), 99);
        float xv = embed[z * H + tid];
        xs[tid] = xv;
        x[j * H + tid] = xv;
    }

    int padded;
    {
        int i = tid;
        float dx = pos[i * 3 + 0] - pjx;
        float dy = pos[i * 3 + 1] - pjy;
        float dz = pos[i * 3 + 2] - pjz;
        float d2 = dx * dx + dy * dy + dz * dz;
        int valid = (d2 < 25.0f) && (i != j);
        unsigned long long m = __ballot(valid);
        int pre = __popcll(m & ((1ull << lane) - 1ull));
        if (lane == 0) wsum8[wave] = __popcll(m);
        __syncthreads();
        int wbase = 0, total = 0;
        for (int w = 0; w < 8; w++) {
            if (w < wave) wbase += wsum8[w];
            total += wsum8[w];
        }
        if (valid) nbr[j * 512 + wbase + pre] = i;
        padded = (total + 63) & ~63;
        for (int s = total + tid; s < padded; s += 512) nbr[j * 512 + s] = j;
        if (tid == 0) ncnt[j] = total;
    }

    // a = b1 + xs @ Wx, 4-way split-K (Wx = first H rows of layer-0 msg_w1)
    {
        float p0 = 0.f, p1 = 0.f, p2 = 0.f, p3 = 0.f;
        int k0 = grp * 32;
#pragma unroll 8
        for (int k = 0; k < 32; k += 4) {
            p0 += xs[k0 + k]     * msg_w1[(k0 + k)     * H + h];
            p1 += xs[k0 + k + 1] * msg_w1[(k0 + k + 1) * H + h];
            p2 += xs[k0 + k + 2] * msg_w1[(k0 + k + 2) * H + h];
            p3 += xs[k0 + k + 3] * msg_w1[(k0 + k + 3) * H + h];
        }
        part[grp][h] = (p0 + p1) + (p2 + p3);
    }
    __syncthreads();   // part ready; nbr writes visible block-wide
    if (grp == 0)
        a[j * H + h] = part[0][h] + part[1][h] + part[2][h] + part[3][h] + b1[h];

    // ---- F feature precompute: 4 threads per slot, 16 features each ----
    const float DELTA = 5.0f / 49.0f;
    int kb = (tid & 3) * 16;
#pragma unroll
    for (int pass = 0; pass < 4; pass++) {
        int slot = pass * 128 + (tid >> 2);
        if (slot < padded) {
            int ni = nbr[j * 512 + slot];
            float dx = pos[ni * 3 + 0] - pjx;
            float dy = pos[ni * 3 + 1] - pjy;
            float dz = pos[ni * 3 + 2] - pjz;
            float d = sqrtf(dx * dx + dy * dy + dz * dz);
            float rinv = 1.0f / fmaxf(d, 1e-8f);
            unsigned short vals[16];
#pragma unroll
            for (int qq = 0; qq < 16; qq++) {
                int k = kb + qq;
                float v;
                if (k < NUM_RBF) {
                    float tt = d - (float)k * DELTA;
                    v = __expf(-50.0f * tt * tt);      // 1/(2*0.1^2) = 50
                } else if (k == NUM_RBF)     v = dx * rinv;
                else if (k == NUM_RBF + 1)   v = dy * rinv;
                else if (k == NUM_RBF + 2)   v = dz * rinv;
                else                         v = 0.0f;
                vals[qq] = f2bf(v);
            }
            int row = slot & 63;
            unsigned short* tile = Fg + (((size_t)(j * MAXS + (slot >> 6))) << 12);
            int c0 = kb >> 3;          // 16B-chunk index (8 shorts per chunk)
            int4v p0, p1;
#pragma unroll
            for (int q = 0; q < 4; q++) {
                p0[q] = (int)((unsigned)vals[2 * q]     | ((unsigned)vals[2 * q + 1] << 16));
                p1[q] = (int)((unsigned)vals[8 + 2 * q] | ((unsigned)vals[9 + 2 * q] << 16));
            }
            *(int4v*)(tile + row * 64 + (((c0    ) ^ (row & 7)) << 3)) = p0;
            *(int4v*)(tile + row * 64 + (((c0 + 1) ^ (row & 7)) << 3)) = p1;
        }
    }

    // ---- Wpack: block j<L packs layer j's Wfeat fragments (16KB bf16) ----
    if (j < L) {
        const float* wf = msg_w1 + j * (H + NUM_RBF + 3) * H + H * H;
        unsigned short* wl = Wpack + j * 8192;
        int wv4w = tid >> 7;
        int rem = tid & 127;
        int ln = rem >> 1;          // lane 0..63
        int c = rem & 1;
        int qd = ln >> 4, nnw = ln & 15;
#pragma unroll
        for (int t = 0; t < 2; t++) {
            int hh = wv4w * 32 + t * 16 + nnw;
            int4v pk;
#pragma unroll
            for (int q = 0; q < 4; q++) {
                int k0 = c * 32 + qd * 8 + 2 * q;
                float v0 = (k0     < NUM_RBF + 3) ? wf[(k0)     * H + hh] : 0.0f;
                float v1 = (k0 + 1 < NUM_RBF + 3) ? wf[(k0 + 1) * H + hh] : 0.0f;
                pk[q] = (int)((unsigned)f2bf(v0) | ((unsigned)f2bf(v1) << 16));
            }
            *(int4v*)(wl + ((wv4w * 64 + ln) * 4 + c * 2 + t) * 8) = pk;
        }
    }
}

// Fused per-layer kernel (R4 staged structure + Wpack bfrag).
// Block b processes node j = order[rank], rank = b<256 ? b : 767-b (cnt-sorted
// order; blocks b and b+256 co-reside on one CU [m09] -> per-CU work ~const).
// F tiles double-buffered per wave-group, prefetched via global_load_lds.
// R7 lesson: NO in-kernel cross-block handoff (threadfence ticket cost 145us).
__global__ __launch_bounds__(512) void k_layer(const float* __restrict__ a,
                                               const int* __restrict__ nbr,
                                               const int* __restrict__ ncnt,
                                               const unsigned short* __restrict__ Fg,
                                               const unsigned short* __restrict__ wpack,
                                               const float* __restrict__ w2,
                                               const float* __restrict__ b2,
                                               const float* __restrict__ u1,
                                               const float* __restrict__ ub1,
                                               const float* __restrict__ u2,
                                               const float* __restrict__ ub2,
                                               float* __restrict__ x,
                                               const float* __restrict__ wxn,
                                               const float* __restrict__ b1n,
                                               float* __restrict__ a_next,
                                               const int* __restrict__ order_in,
                                               int* __restrict__ order_out) {
    int b = blockIdx.x;
    int tid = threadIdx.x;
    int g = tid >> 8;          // wave-group 0..1
    int lane = tid & 63;
    int wv4 = (tid >> 6) & 3;  // wave within group
    int nn = lane & 15;
    int quad = lane >> 4;
    int hbase = wv4 * 32;

    __shared__ __align__(16) unsigned short F[2][2][SUPER * 64];  // [group][buf]
    __shared__ __align__(16) int nidx_all[512];
    __shared__ __align__(16) int cnts_l[512];
    __shared__ int order_l[512];
    __shared__ float sjp[2][H];
    __shared__ float sj[H], xj[H], ag[H], hid[H], xn[H];
    __shared__ float part[4][H];

    int rank = (b < 256) ? b : 767 - b;   // pair (b, b+256) -> ranks summing 511
    int j;
    if (order_in != nullptr) {
        j = order_in[rank];
    } else {
        cnts_l[tid] = ncnt[tid];
        __syncthreads();
        int c_t = cnts_l[tid];
        int r = 0;
#pragma unroll 4
        for (int i = 0; i < 512; i += 4) {
            int4v c4 = *(const int4v*)&cnts_l[i];
            r += (c4[0] < c_t || (c4[0] == c_t && (i    ) < tid)) ? 1 : 0;
            r += (c4[1] < c_t || (c4[1] == c_t && (i + 1) < tid)) ? 1 : 0;
            r += (c4[2] < c_t || (c4[2] == c_t && (i + 2) < tid)) ? 1 : 0;
            r += (c4[3] < c_t || (c4[3] == c_t && (i + 3) < tid)) ? 1 : 0;
        }
        order_l[r] = tid;      // strict total order -> bijection
        __syncthreads();
        j = order_l[rank];
        if (order_out != nullptr && b == 0) order_out[tid] = order_l[tid];
    }

    int cnt = ncnt[j];

    if (tid < 2 * H) sjp[tid >> 7][tid & 127] = 0.0f;
    if (tid < H) xj[tid] = x[j * H + tid];
    nidx_all[tid] = nbr[j * 512 + tid];   // all 512 slots, once

    // bfrag: 4 coalesced dwordx4 from Wpack (fragment-linear)
    short8 bfrag[2][2];
    {
        const unsigned short* wp = wpack + (wv4 * 64 + lane) * 32;
        bfrag[0][0] = *(const short8*)(wp);
        bfrag[0][1] = *(const short8*)(wp + 8);
        bfrag[1][0] = *(const short8*)(wp + 16);
        bfrag[1][1] = *(const short8*)(wp + 24);
    }

    int S = (cnt + 63) >> 6;
    int rounds = (S + 1) >> 1;

    // stage one 8KB F tile (64x64 shorts) into F[g][buf] via 8 async 1KB copies
    auto stage_tile = [&](int s, int buf) {
        const char* src = (const char*)(Fg + (((size_t)(j * MAXS + s)) << 12));
        char* dst = (char*)&F[g][buf][0];
#pragma unroll
        for (int q = 0; q < 2; q++) {
            int off = (wv4 + 4 * q) << 10;           // wave-uniform
            gld_lds16(src + off + lane * 16, dst + off);
        }
    };

    // prologue: stage s = g into buf 0
    if (g < S) stage_tile(g, 0);
    __syncthreads();   // drains vmcnt -> buf 0 ready, nidx_all ready

    float pacc0 = 0.0f, pacc1 = 0.0f;

    for (int r = 0; r < rounds; r++) {
        int s = 2 * r + g;
        int sn = 2 * (r + 1) + g;
        if (sn < S) stage_tile(sn, (r + 1) & 1);   // async, in flight under compute
        if (s < S) {
            int cur = r & 1;
#pragma unroll
            for (int it = 0; it < SUPER / 16; it++) {
                int lbase = it * 16 + quad * 4;
                int4v ni4 = *(const int4v*)&nidx_all[s * 64 + lbase];
                float av0[4], av1[4];
#pragma unroll
                for (int rr = 0; rr < 4; rr++) {
                    av0[rr] = a[ni4[rr] * H + hbase + nn];
                    av1[rr] = a[ni4[rr] * H + hbase + 16 + nn];
                }
                int row = it * 16 + nn;
                const char* fb = (const char*)&F[g][cur][0] + row * 128;
                short8 afrag0 = *(const short8*)(fb + ((quad       ^ (row & 7)) << 4));
                short8 afrag1 = *(const short8*)(fb + (((quad + 4) ^ (row & 7)) << 4));
                float4v acc0 = {0.0f, 0.0f, 0.0f, 0.0f};
                float4v acc1 = {0.0f, 0.0f, 0.0f, 0.0f};
                acc0 = __builtin_amdgcn_mfma_f32_16x16x32_bf16(afrag0, bfrag[0][0], acc0, 0, 0, 0);
                acc0 = __builtin_amdgcn_mfma_f32_16x16x32_bf16(afrag1, bfrag[1][0], acc0, 0, 0, 0);
                acc1 = __builtin_amdgcn_mfma_f32_16x16x32_bf16(afrag0, bfrag[0][1], acc1, 0, 0, 0);
                acc1 = __builtin_amdgcn_mfma_f32_16x16x32_bf16(afrag1, bfrag[1][1], acc1, 0, 0, 0);
#pragma unroll
                for (int rr = 0; rr < 4; rr++) {
                    float vm = (s * 64 + lbase + rr < cnt) ? 1.0f : 0.0f;
                    pacc0 += vm * silu_f(acc0[rr] + av0[rr]);
                    pacc1 += vm * silu_f(acc1[rr] + av1[rr]);
                }
            }
        }
        __syncthreads();   // one barrier per round (also drains staged loads)
    }

    // group partial -> LDS (quad shuffle-reduce; lanes 0..15 of each wave write)
    pacc0 += __shfl_xor(pacc0, 16, 64);
    pacc0 += __shfl_xor(pacc0, 32, 64);
    pacc1 += __shfl_xor(pacc1, 16, 64);
    pacc1 += __shfl_xor(pacc1, 32, 64);
    if (lane < 16) {
        sjp[g][hbase + lane]      = pacc0;
        sjp[g][hbase + 16 + lane] = pacc1;
    }
    __syncthreads();
    if (tid < H) sj[tid] = sjp[0][tid] + sjp[1][tid];
    __syncthreads();

    // ---- inline update: 4-way split-K MLP on 512 threads ----
    int h = tid & 127;
    int grp = tid >> 7;   // 0..3

    {
        float p0 = 0.f, p1 = 0.f, p2 = 0.f, p3 = 0.f;
        int k0 = grp * 32;
#pragma unroll 8
        for (int k = 0; k < 32; k += 4) {
            p0 += sj[k0 + k]     * w2[(k0 + k)     * H + h];
            p1 += sj[k0 + k + 1] * w2[(k0 + k + 1) * H + h];
            p2 += sj[k0 + k + 2] * w2[(k0 + k + 2) * H + h];
            p3 += sj[k0 + k + 3] * w2[(k0 + k + 3) * H + h];
        }
        part[grp][h] = (p0 + p1) + (p2 + p3);
    }
    __syncthreads();
    if (grp == 0) ag[h] = part[0][h] + part[1][h] + part[2][h] + part[3][h] + (float)cnt * b2[h];
    __syncthreads();

    {
        const float* src = (grp < 2) ? xj : ag;
        int sbase = (grp & 1) * 64;
        int k0 = grp * 64;
        float p0 = 0.f, p1 = 0.f, p2 = 0.f, p3 = 0.f;
#pragma unroll 8
        for (int k = 0; k < 64; k += 4) {
            p0 += src[sbase + k]     * u1[(k0 + k)     * H + h];
            p1 += src[sbase + k + 1] * u1[(k0 + k + 1) * H + h];
            p2 += src[sbase + k + 2] * u1[(k0 + k + 2) * H + h];
            p3 += src[sbase + k + 3] * u1[(k0 + k + 3) * H + h];
        }
        part[grp][h] = (p0 + p1) + (p2 + p3);
    }
    __syncthreads();
    if (grp == 0) hid[h] = silu_f(part[0][h] + part[1][h] + part[2][h] + part[3][h] + ub1[h]);
    __syncthreads();

    {
        float p0 = 0.f, p1 = 0.f, p2 = 0.f, p3 = 0.f;
        int k0 = grp * 32;
#pragma unroll 8
        for (int k = 0; k < 32; k += 4) {
            p0 += hid[k0 + k]     * u2[(k0 + k)     * H + h];
            p1 += hid[k0 + k + 1] * u2[(k0 + k + 1) * H + h];
            p2 += hid[k0 + k + 2] * u2[(k0 + k + 2) * H + h];
            p3 += hid[k0 + k + 3] * u2[(k0 + k + 3) * H + h];
        }
        part[grp][h] = (p0 + p1) + (p2 + p3);
    }
    __syncthreads();
    if (grp == 0) {
        float xv = xj[h] + part[0][h] + part[1][h] + part[2][h] + part[3][h] + ub2[h];
        x[j * H + h] = xv;
        xn[h] = xv;
    }

    if (a_next != nullptr) {
        __syncthreads();
        float p0 = 0.f, p1 = 0.f, p2 = 0.f, p3 = 0.f;
        int k0 = grp * 32;
#pragma unroll 8
        for (int k = 0; k < 32; k += 4) {
            p0 += xn[k0 + k]     * wxn[(k0 + k)     * H + h];
            p1 += xn[k0 + k + 1] * wxn[(k0 + k + 1) * H + h];
            p2 += xn[k0 + k + 2] * wxn[(k0 + k + 2) * H + h];
            p3 += xn[k0 + k + 3] * wxn[(k0 + k + 3) * H + h];
        }
        part[grp][h] = (p0 + p1) + (p2 + p3);
        __syncthreads();
        if (grp == 0)
            a_next[j * H + h] = part[0][h] + part[1][h] + part[2][h] + part[3][h] + b1n[h];
    }
}

// per-molecule mean pool + 2-layer output MLP. batch is SORTED (reference does
// jnp.sort): binary-search the [lo,hi) row range per molecule. 512 threads:
// 4-way split of the row-sum to shorten the serial load chain.
__global__ __launch_bounds__(512) void k_pool(const float* __restrict__ x,
                                              const int* __restrict__ batch,
                                              const float* __restrict__ ow1,
                                              const float* __restrict__ ob1,
                                              const float* __restrict__ ow2,
                                              const float* __restrict__ ob2,
                                              float* __restrict__ out) {
    int m = blockIdx.x;
    int tid = threadIdx.x;
    int h = tid & 127;
    int q = tid >> 7;
    __shared__ int lo_s, hi_s;
    __shared__ float psum[4][H];
    __shared__ float pooled[H];
    __shared__ float hid[H / 2];

    if (tid == 0) {
        int a = 0, b = N;
        while (a < b) { int mid = (a + b) >> 1; if (batch[mid] < m) a = mid + 1; else b = mid; }
        lo_s = a;
        b = N;
        while (a < b) { int mid = (a + b) >> 1; if (batch[mid] < m + 1) a = mid + 1; else b = mid; }
        hi_s = a;
    }
    __syncthreads();

    int lo = lo_s, hi = hi_s;
    float s = 0.0f;
    for (int i = lo + q; i < hi; i += 4) s += x[i * H + h];
    psum[q][h] = s;
    __syncthreads();
    if (q == 0) pooled[h] = (psum[0][h] + psum[1][h] + psum[2][h] + psum[3][h]) / (float)max(hi - lo, 1);
    __syncthreads();

    if (tid < H / 2) {
        float p0 = 0.f, p1 = 0.f;
        for (int k = 0; k < H; k += 2) {
            p0 += pooled[k]     * ow1[(k)     * (H / 2) + h];
            p1 += pooled[k + 1] * ow1[(k + 1) * (H / 2) + h];
        }
        hid[h] = silu_f(p0 + p1 + ob1[h]);
    }
    __syncthreads();

    if (tid == 0) {
        float o = ob2[0];
        for (int k = 0; k < H / 2; k++) o += hid[k] * ow2[k];
        out[m] = o;
    }
}

extern "C" void kernel_launch(void* const* d_in, const int* in_sizes, int n_in,
                              void* d_out, int out_size, void* d_ws, size_t ws_size,
                              hipStream_t stream) {
    const int*   an      = (const int*)d_in[0];
    const float* pos     = (const float*)d_in[1];
    const int*   batch   = (const int*)d_in[2];
    const float* embed   = (const float*)d_in[3];
    const float* msg_w1  = (const float*)d_in[4];   // L x 181 x 128
    const float* msg_b1  = (const float*)d_in[5];
    const float* msg_w2  = (const float*)d_in[6];   // L x 128 x 128
    const float* msg_b2  = (const float*)d_in[7];
    const float* upd_w1  = (const float*)d_in[8];   // L x 256 x 128
    const float* upd_b1  = (const float*)d_in[9];
    const float* upd_w2  = (const float*)d_in[10];  // L x 128 x 128
    const float* upd_b2  = (const float*)d_in[11];
    const float* out_w1  = (const float*)d_in[12];  // 128 x 64
    const float* out_b1  = (const float*)d_in[13];
    const float* out_w2  = (const float*)d_in[14];  // 64 x 1
    const float* out_b2  = (const float*)d_in[15];
    float* out = (float*)d_out;

    float* x    = (float*)d_ws;                          // N*H
    float* a0   = x + N * H;                             // N*H (even layers)
    float* a1   = a0 + N * H;                            // N*H (odd layers)
    int*   nbr  = (int*)(a1 + N * H);                    // N*512
    int*   ncnt = nbr + N * 512;                         // N
    int*   order_g = ncnt + N;                           // N (cnt-sorted node order)
    unsigned short* Wpack = (unsigned short*)(order_g + N); // L*8192 shorts (64 KB)
    unsigned short* Fg = Wpack + L * 8192;               // N*MAXS*4096 shorts (32 MB)

    const int W1ROWS = H + NUM_RBF + 3;  // 181

    k_embed_lin<<<N, 512, 0, stream>>>(an, embed, pos, msg_w1, msg_b1, x, a0,
                                       nbr, ncnt, Fg, Wpack);
    for (int l = 0; l < L; l++) {
        float* a_cur  = (l & 1) ? a1 : a0;
        float* a_next = (l + 1 < L) ? ((l & 1) ? a0 : a1) : nullptr;
        const float* wxn = (l + 1 < L) ? (msg_w1 + (l + 1) * W1ROWS * H) : nullptr;
        const float* b1n = (l + 1 < L) ? (msg_b1 + (l + 1) * H) : nullptr;
        const int* oin  = (l == 0) ? nullptr : order_g;
        int*       oout = (l == 0) ? order_g : nullptr;
        k_layer<<<N, 512, 0, stream>>>(a_cur, nbr, ncnt, Fg, Wpack + l * 8192,
                                       msg_w2 + l * H * H, msg_b2 + l * H,
                                       upd_w1 + l * 2 * H * H, upd_b1 + l * H,
                                       upd_w2 + l * H * H, upd_b2 + l * H,
                                       x, wxn, b1n, a_next, oin, oout);
    }
    k_pool<<<NMOL, 512, 0, stream>>>(x, batch, out_w1, out_b1, out_w2, out_b2, out);
}

// Round 9
// 198.384 us; speedup vs baseline: 1.7822x; 1.0058x over previous
//
#include <hip/hip_runtime.h>
#include <math.h>

#define N 512
#define H 128
#define L 4
#define NUM_RBF 50
#define NMOL 16
#define SUPER 64          // neighbor slots per super-tile
#define MAXS 8            // max super-tiles per node (ceil(511/64))

typedef __attribute__((ext_vector_type(8))) short short8;
typedef __attribute__((ext_vector_type(4))) float float4v;
typedef __attribute__((ext_vector_type(4))) int int4v;

// silu via v_rcp (1 ulp) instead of exact-div expansion (~8 instr, 2 trans-rate)
__device__ __forceinline__ float silu_f(float v) {
    return v * __builtin_amdgcn_rcpf(1.0f + __expf(-v));
}

__device__ __forceinline__ unsigned short f2bf(float f) {
    unsigned int u = __float_as_uint(f);
    unsigned int r = (u + 0x7FFFu + ((u >> 16) & 1u)) >> 16;  // RNE
    return (unsigned short)r;
}

// async 16B global->LDS copy. dst must be WAVE-UNIFORM; HW adds lane*16.
__device__ __forceinline__ void gld_lds16(const void* g, void* l) {
    __builtin_amdgcn_global_load_lds(
        (const __attribute__((address_space(1))) unsigned int*)g,
        (__attribute__((address_space(3))) unsigned int*)l, 16, 0, 0);
}

// Per block j (512 threads):
//  - ballot-compact valid neighbors (d<5, i!=j) into nbr[j*512..], pad to x64 with j
//  - x[j,h] = embed row;  a[j,h] = b1[h] + x[j,:] @ Wx[:,h]  (4-way split-K)
//  - precompute layer-invariant bf16 feature tiles F (rbf+dirs, 53->64 padded)
//    per (j, supertile): 64 rows x 64 shorts, 16B-chunk XOR swizzle c^(r&7)
//    (linear LDS dest for global_load_lds + conflict-floor ds_read_b128).
//    R6 lesson: Fg (32MB) is NOT cache-resident; k_layer must PREFETCH it via
//    global_load_lds (decoupled DMA), not demand-load it (274 GB/s, 52us).
//  - blocks j<L pack layer j's Wfeat into fragment-linear bf16 (Wpack,
//    16KB/layer) so k_layer's bfrag is 4 coalesced dwordx4 loads.
__global__ __launch_bounds__(512) void k_embed_lin(const int* __restrict__ an,
                                                   const float* __restrict__ embed,
                                                   const float* __restrict__ pos,
                                                   const float* __restrict__ msg_w1,
                                                   const float* __restrict__ b1,
                                                   float* __restrict__ x,
                                                   float* __restrict__ a,
                                                   int* __restrict__ nbr,
                                                   int* __restrict__ ncnt,
                                                   unsigned short* __restrict__ Fg,
                                                   unsigned short* __restrict__ Wpack) {
    int j = blockIdx.x;
    int tid = threadIdx.x;
    int lane = tid & 63;
    int wave = tid >> 6;
    int h = tid & 127;
    int grp = tid >> 7;

    __shared__ float xs[H];
    __shared__ int wsum8[8];
    __shared__ float part[4][H];

    float pjx = pos[j * 3 + 0], pjy = pos[j * 3 + 1], pjz = pos[j * 3 + 2];

    if (tid < H) {
        int z = an[j];
        z = min(max(z, 0), 99);
        float xv = embed[z * H + tid];
        xs[tid] = xv;
        x[j * H + tid] = xv;
    }

    int padded;
    {
        int i = tid;
        float dx = pos[i * 3 + 0] - pjx;
        float dy = pos[i * 3 + 1] - pjy;
        float dz = pos[i * 3 + 2] - pjz;
        float d2 = dx * dx + dy * dy + dz * dz;
        int valid = (d2 < 25.0f) && (i != j);
        unsigned long long m = __ballot(valid);
        int pre = __popcll(m & ((1ull << lane) - 1ull));
        if (lane == 0) wsum8[wave] = __popcll(m);
        __syncthreads();
        int wbase = 0, total = 0;
        for (int w = 0; w < 8; w++) {
            if (w < wave) wbase += wsum8[w];
            total += wsum8[w];
        }
        if (valid) nbr[j * 512 + wbase + pre] = i;
        padded = (total + 63) & ~63;
        for (int s = total + tid; s < padded; s += 512) nbr[j * 512 + s] = j;
        if (tid == 0) ncnt[j] = total;
    }

    // a = b1 + xs @ Wx, 4-way split-K (Wx = first H rows of layer-0 msg_w1)
    {
        float p0 = 0.f, p1 = 0.f, p2 = 0.f, p3 = 0.f;
        int k0 = grp * 32;
#pragma unroll 8
        for (int k = 0; k < 32; k += 4) {
            p0 += xs[k0 + k]     * msg_w1[(k0 + k)     * H + h];
            p1 += xs[k0 + k + 1] * msg_w1[(k0 + k + 1) * H + h];
            p2 += xs[k0 + k + 2] * msg_w1[(k0 + k + 2) * H + h];
            p3 += xs[k0 + k + 3] * msg_w1[(k0 + k + 3) * H + h];
        }
        part[grp][h] = (p0 + p1) + (p2 + p3);
    }
    __syncthreads();   // part ready; nbr writes visible block-wide
    if (grp == 0)
        a[j * H + h] = part[0][h] + part[1][h] + part[2][h] + part[3][h] + b1[h];

    // ---- F feature precompute: 4 threads per slot, 16 features each ----
    const float DELTA = 5.0f / 49.0f;
    int kb = (tid & 3) * 16;
#pragma unroll
    for (int pass = 0; pass < 4; pass++) {
        int slot = pass * 128 + (tid >> 2);
        if (slot < padded) {
            int ni = nbr[j * 512 + slot];
            float dx = pos[ni * 3 + 0] - pjx;
            float dy = pos[ni * 3 + 1] - pjy;
            float dz = pos[ni * 3 + 2] - pjz;
            float d = sqrtf(dx * dx + dy * dy + dz * dz);
            float rinv = 1.0f / fmaxf(d, 1e-8f);
            unsigned short vals[16];
#pragma unroll
            for (int qq = 0; qq < 16; qq++) {
                int k = kb + qq;
                float v;
                if (k < NUM_RBF) {
                    float tt = d - (float)k * DELTA;
                    v = __expf(-50.0f * tt * tt);      // 1/(2*0.1^2) = 50
                } else if (k == NUM_RBF)     v = dx * rinv;
                else if (k == NUM_RBF + 1)   v = dy * rinv;
                else if (k == NUM_RBF + 2)   v = dz * rinv;
                else                         v = 0.0f;
                vals[qq] = f2bf(v);
            }
            int row = slot & 63;
            unsigned short* tile = Fg + (((size_t)(j * MAXS + (slot >> 6))) << 12);
            int c0 = kb >> 3;          // 16B-chunk index (8 shorts per chunk)
            int4v p0, p1;
#pragma unroll
            for (int q = 0; q < 4; q++) {
                p0[q] = (int)((unsigned)vals[2 * q]     | ((unsigned)vals[2 * q + 1] << 16));
                p1[q] = (int)((unsigned)vals[8 + 2 * q] | ((unsigned)vals[9 + 2 * q] << 16));
            }
            *(int4v*)(tile + row * 64 + (((c0    ) ^ (row & 7)) << 3)) = p0;
            *(int4v*)(tile + row * 64 + (((c0 + 1) ^ (row & 7)) << 3)) = p1;
        }
    }

    // ---- Wpack: block j<L packs layer j's Wfeat fragments (16KB bf16) ----
    if (j < L) {
        const float* wf = msg_w1 + j * (H + NUM_RBF + 3) * H + H * H;
        unsigned short* wl = Wpack + j * 8192;
        int wv4w = tid >> 7;
        int rem = tid & 127;
        int ln = rem >> 1;          // lane 0..63
        int c = rem & 1;
        int qd = ln >> 4, nnw = ln & 15;
#pragma unroll
        for (int t = 0; t < 2; t++) {
            int hh = wv4w * 32 + t * 16 + nnw;
            int4v pk;
#pragma unroll
            for (int q = 0; q < 4; q++) {
                int k0 = c * 32 + qd * 8 + 2 * q;
                float v0 = (k0     < NUM_RBF + 3) ? wf[(k0)     * H + hh] : 0.0f;
                float v1 = (k0 + 1 < NUM_RBF + 3) ? wf[(k0 + 1) * H + hh] : 0.0f;
                pk[q] = (int)((unsigned)f2bf(v0) | ((unsigned)f2bf(v1) << 16));
            }
            *(int4v*)(wl + ((wv4w * 64 + ln) * 4 + c * 2 + t) * 8) = pk;
        }
    }
}

// Fused per-layer kernel (R4 staged structure + Wpack bfrag + wave-level tail).
// Block b processes node j = order[rank], rank = b<256 ? b : 767-b (cnt-sorted
// order; blocks b and b+256 co-reside on one CU [m09] -> per-CU work ~const).
// F tiles double-buffered per wave-group, prefetched via global_load_lds.
// R7 lesson: NO in-kernel cross-block handoff (threadfence ticket cost 145us).
// R9: update tail uses wave-level split-K (output o = wave*16+(lane&15),
// k-part p = lane>>4, quad reduce via 2x shfl_xor) -> 3 barriers instead of 8,
// no part[][] LDS roundtrip, all 512 threads active every stage.
__global__ __launch_bounds__(512) void k_layer(const float* __restrict__ a,
                                               const int* __restrict__ nbr,
                                               const int* __restrict__ ncnt,
                                               const unsigned short* __restrict__ Fg,
                                               const unsigned short* __restrict__ wpack,
                                               const float* __restrict__ w2,
                                               const float* __restrict__ b2,
                                               const float* __restrict__ u1,
                                               const float* __restrict__ ub1,
                                               const float* __restrict__ u2,
                                               const float* __restrict__ ub2,
                                               float* __restrict__ x,
                                               const float* __restrict__ wxn,
                                               const float* __restrict__ b1n,
                                               float* __restrict__ a_next,
                                               const int* __restrict__ order_in,
                                               int* __restrict__ order_out) {
    int b = blockIdx.x;
    int tid = threadIdx.x;
    int g = tid >> 8;          // wave-group 0..1
    int lane = tid & 63;
    int wv4 = (tid >> 6) & 3;  // wave within group
    int nn = lane & 15;
    int quad = lane >> 4;
    int hbase = wv4 * 32;

    __shared__ __align__(16) unsigned short F[2][2][SUPER * 64];  // [group][buf]
    __shared__ __align__(16) int nidx_all[512];
    __shared__ __align__(16) int cnts_l[512];
    __shared__ int order_l[512];
    __shared__ float sjp[2][H];
    __shared__ float sj[H], xj[H], ag[H], hid[H], xn[H];

    int rank = (b < 256) ? b : 767 - b;   // pair (b, b+256) -> ranks summing 511
    int j;
    if (order_in != nullptr) {
        j = order_in[rank];
    } else {
        cnts_l[tid] = ncnt[tid];
        __syncthreads();
        int c_t = cnts_l[tid];
        int r = 0;
#pragma unroll 4
        for (int i = 0; i < 512; i += 4) {
            int4v c4 = *(const int4v*)&cnts_l[i];
            r += (c4[0] < c_t || (c4[0] == c_t && (i    ) < tid)) ? 1 : 0;
            r += (c4[1] < c_t || (c4[1] == c_t && (i + 1) < tid)) ? 1 : 0;
            r += (c4[2] < c_t || (c4[2] == c_t && (i + 2) < tid)) ? 1 : 0;
            r += (c4[3] < c_t || (c4[3] == c_t && (i + 3) < tid)) ? 1 : 0;
        }
        order_l[r] = tid;      // strict total order -> bijection
        __syncthreads();
        j = order_l[rank];
        if (order_out != nullptr && b == 0) order_out[tid] = order_l[tid];
    }

    int cnt = ncnt[j];

    if (tid < 2 * H) sjp[tid >> 7][tid & 127] = 0.0f;
    if (tid < H) xj[tid] = x[j * H + tid];
    nidx_all[tid] = nbr[j * 512 + tid];   // all 512 slots, once

    // bfrag: 4 coalesced dwordx4 from Wpack (fragment-linear)
    short8 bfrag[2][2];
    {
        const unsigned short* wp = wpack + (wv4 * 64 + lane) * 32;
        bfrag[0][0] = *(const short8*)(wp);
        bfrag[0][1] = *(const short8*)(wp + 8);
        bfrag[1][0] = *(const short8*)(wp + 16);
        bfrag[1][1] = *(const short8*)(wp + 24);
    }

    int S = (cnt + 63) >> 6;
    int rounds = (S + 1) >> 1;

    // stage one 8KB F tile (64x64 shorts) into F[g][buf] via 8 async 1KB copies
    auto stage_tile = [&](int s, int buf) {
        const char* src = (const char*)(Fg + (((size_t)(j * MAXS + s)) << 12));
        char* dst = (char*)&F[g][buf][0];
#pragma unroll
        for (int q = 0; q < 2; q++) {
            int off = (wv4 + 4 * q) << 10;           // wave-uniform
            gld_lds16(src + off + lane * 16, dst + off);
        }
    };

    // prologue: stage s = g into buf 0
    if (g < S) stage_tile(g, 0);
    __syncthreads();   // drains vmcnt -> buf 0 ready, nidx_all ready

    float pacc0 = 0.0f, pacc1 = 0.0f;

    for (int r = 0; r < rounds; r++) {
        int s = 2 * r + g;
        int sn = 2 * (r + 1) + g;
        if (sn < S) stage_tile(sn, (r + 1) & 1);   // async, in flight under compute
        if (s < S) {
            int cur = r & 1;
#pragma unroll
            for (int it = 0; it < SUPER / 16; it++) {
                int lbase = it * 16 + quad * 4;
                int4v ni4 = *(const int4v*)&nidx_all[s * 64 + lbase];
                float av0[4], av1[4];
#pragma unroll
                for (int rr = 0; rr < 4; rr++) {
                    av0[rr] = a[ni4[rr] * H + hbase + nn];
                    av1[rr] = a[ni4[rr] * H + hbase + 16 + nn];
                }
                int row = it * 16 + nn;
                const char* fb = (const char*)&F[g][cur][0] + row * 128;
                short8 afrag0 = *(const short8*)(fb + ((quad       ^ (row & 7)) << 4));
                short8 afrag1 = *(const short8*)(fb + (((quad + 4) ^ (row & 7)) << 4));
                float4v acc0 = {0.0f, 0.0f, 0.0f, 0.0f};
                float4v acc1 = {0.0f, 0.0f, 0.0f, 0.0f};
                acc0 = __builtin_amdgcn_mfma_f32_16x16x32_bf16(afrag0, bfrag[0][0], acc0, 0, 0, 0);
                acc0 = __builtin_amdgcn_mfma_f32_16x16x32_bf16(afrag1, bfrag[1][0], acc0, 0, 0, 0);
                acc1 = __builtin_amdgcn_mfma_f32_16x16x32_bf16(afrag0, bfrag[0][1], acc1, 0, 0, 0);
                acc1 = __builtin_amdgcn_mfma_f32_16x16x32_bf16(afrag1, bfrag[1][1], acc1, 0, 0, 0);
#pragma unroll
                for (int rr = 0; rr < 4; rr++) {
                    float vm = (s * 64 + lbase + rr < cnt) ? 1.0f : 0.0f;
                    pacc0 += vm * silu_f(acc0[rr] + av0[rr]);
                    pacc1 += vm * silu_f(acc1[rr] + av1[rr]);
                }
            }
        }
        __syncthreads();   // one barrier per round (also drains staged loads)
    }

    // group partial -> LDS (quad shuffle-reduce; lanes 0..15 of each wave write)
    pacc0 += __shfl_xor(pacc0, 16, 64);
    pacc0 += __shfl_xor(pacc0, 32, 64);
    pacc1 += __shfl_xor(pacc1, 16, 64);
    pacc1 += __shfl_xor(pacc1, 32, 64);
    if (lane < 16) {
        sjp[g][hbase + lane]      = pacc0;
        sjp[g][hbase + 16 + lane] = pacc1;
    }
    __syncthreads();
    if (tid < H) sj[tid] = sjp[0][tid] + sjp[1][tid];
    __syncthreads();

    // ---- inline update: wave-level split-K, 1 barrier per stage ----
    // output o = wave*16 + (lane&15); k-part p = lane>>4; reduce via shfl_xor.
    int wv = tid >> 6;                 // wave 0..7
    int o  = wv * 16 + (lane & 15);    // output 0..127 (distinct per wave)
    int p  = lane >> 4;                // k-part 0..3

    // ag = sj @ w2 + cnt*b2
    {
        float r0 = 0.f, r1 = 0.f;
        const float* wrow = w2 + (p * 32) * H + o;
#pragma unroll 8
        for (int kk = 0; kk < 32; kk += 2) {
            r0 += sj[p * 32 + kk]     * wrow[kk * H];
            r1 += sj[p * 32 + kk + 1] * wrow[(kk + 1) * H];
        }
        float r = r0 + r1;
        r += __shfl_xor(r, 16, 64);
        r += __shfl_xor(r, 32, 64);
        if ((lane & 48) == 0) ag[o] = r + (float)cnt * b2[o];
    }
    __syncthreads();

    // hid = silu([xj | ag] @ u1 + ub1), K = 256; p covers 64 rows each
    {
        float r0 = 0.f, r1 = 0.f;
        const float* src = (p < 2) ? xj : ag;
        int sb = (p & 1) * 64;
        const float* wrow = u1 + (p * 64) * H + o;
#pragma unroll 8
        for (int kk = 0; kk < 64; kk += 2) {
            r0 += src[sb + kk]     * wrow[kk * H];
            r1 += src[sb + kk + 1] * wrow[(kk + 1) * H];
        }
        float r = r0 + r1;
        r += __shfl_xor(r, 16, 64);
        r += __shfl_xor(r, 32, 64);
        if ((lane & 48) == 0) hid[o] = silu_f(r + ub1[o]);
    }
    __syncthreads();

    // x' = x + hid @ u2 + ub2
    {
        float r0 = 0.f, r1 = 0.f;
        const float* wrow = u2 + (p * 32) * H + o;
#pragma unroll 8
        for (int kk = 0; kk < 32; kk += 2) {
            r0 += hid[p * 32 + kk]     * wrow[kk * H];
            r1 += hid[p * 32 + kk + 1] * wrow[(kk + 1) * H];
        }
        float r = r0 + r1;
        r += __shfl_xor(r, 16, 64);
        r += __shfl_xor(r, 32, 64);
        if ((lane & 48) == 0) {
            float xv = xj[o] + r + ub2[o];
            x[j * H + o] = xv;
            xn[o] = xv;
        }
    }

    // a_next = x' @ wxn + b1n
    if (a_next != nullptr) {
        __syncthreads();
        float r0 = 0.f, r1 = 0.f;
        const float* wrow = wxn + (p * 32) * H + o;
#pragma unroll 8
        for (int kk = 0; kk < 32; kk += 2) {
            r0 += xn[p * 32 + kk]     * wrow[kk * H];
            r1 += xn[p * 32 + kk + 1] * wrow[(kk + 1) * H];
        }
        float r = r0 + r1;
        r += __shfl_xor(r, 16, 64);
        r += __shfl_xor(r, 32, 64);
        if ((lane & 48) == 0) a_next[j * H + o] = r + b1n[o];
    }
}

// per-molecule mean pool + 2-layer output MLP. batch is SORTED (reference does
// jnp.sort): binary-search the [lo,hi) row range per molecule. 512 threads:
// 4-way split of the row-sum to shorten the serial load chain.
__global__ __launch_bounds__(512) void k_pool(const float* __restrict__ x,
                                              const int* __restrict__ batch,
                                              const float* __restrict__ ow1,
                                              const float* __restrict__ ob1,
                                              const float* __restrict__ ow2,
                                              const float* __restrict__ ob2,
                                              float* __restrict__ out) {
    int m = blockIdx.x;
    int tid = threadIdx.x;
    int h = tid & 127;
    int q = tid >> 7;
    __shared__ int lo_s, hi_s;
    __shared__ float psum[4][H];
    __shared__ float pooled[H];
    __shared__ float hid[H / 2];

    if (tid == 0) {
        int a = 0, b = N;
        while (a < b) { int mid = (a + b) >> 1; if (batch[mid] < m) a = mid + 1; else b = mid; }
        lo_s = a;
        b = N;
        while (a < b) { int mid = (a + b) >> 1; if (batch[mid] < m + 1) a = mid + 1; else b = mid; }
        hi_s = a;
    }
    __syncthreads();

    int lo = lo_s, hi = hi_s;
    float s = 0.0f;
    for (int i = lo + q; i < hi; i += 4) s += x[i * H + h];
    psum[q][h] = s;
    __syncthreads();
    if (q == 0) pooled[h] = (psum[0][h] + psum[1][h] + psum[2][h] + psum[3][h]) / (float)max(hi - lo, 1);
    __syncthreads();

    if (tid < H / 2) {
        float p0 = 0.f, p1 = 0.f;
        for (int k = 0; k < H; k += 2) {
            p0 += pooled[k]     * ow1[(k)     * (H / 2) + h];
            p1 += pooled[k + 1] * ow1[(k + 1) * (H / 2) + h];
        }
        hid[h] = silu_f(p0 + p1 + ob1[h]);
    }
    __syncthreads();

    if (tid == 0) {
        float o = ob2[0];
        for (int k = 0; k < H / 2; k++) o += hid[k] * ow2[k];
        out[m] = o;
    }
}

extern "C" void kernel_launch(void* const* d_in, const int* in_sizes, int n_in,
                              void* d_out, int out_size, void* d_ws, size_t ws_size,
                              hipStream_t stream) {
    const int*   an      = (const int*)d_in[0];
    const float* pos     = (const float*)d_in[1];
    const int*   batch   = (const int*)d_in[2];
    const float* embed   = (const float*)d_in[3];
    const float* msg_w1  = (const float*)d_in[4];   // L x 181 x 128
    const float* msg_b1  = (const float*)d_in[5];
    const float* msg_w2  = (const float*)d_in[6];   // L x 128 x 128
    const float* msg_b2  = (const float*)d_in[7];
    const float* upd_w1  = (const float*)d_in[8];   // L x 256 x 128
    const float* upd_b1  = (const float*)d_in[9];
    const float* upd_w2  = (const float*)d_in[10];  // L x 128 x 128
    const float* upd_b2  = (const float*)d_in[11];
    const float* out_w1  = (const float*)d_in[12];  // 128 x 64
    const float* out_b1  = (const float*)d_in[13];
    const float* out_w2  = (const float*)d_in[14];  // 64 x 1
    const float* out_b2  = (const float*)d_in[15];
    float* out = (float*)d_out;

    float* x    = (float*)d_ws;                          // N*H
    float* a0   = x + N * H;                             // N*H (even layers)
    float* a1   = a0 + N * H;                            // N*H (odd layers)
    int*   nbr  = (int*)(a1 + N * H);                    // N*512
    int*   ncnt = nbr + N * 512;                         // N
    int*   order_g = ncnt + N;                           // N (cnt-sorted node order)
    unsigned short* Wpack = (unsigned short*)(order_g + N); // L*8192 shorts (64 KB)
    unsigned short* Fg = Wpack + L * 8192;               // N*MAXS*4096 shorts (32 MB)

    const int W1ROWS = H + NUM_RBF + 3;  // 181

    k_embed_lin<<<N, 512, 0, stream>>>(an, embed, pos, msg_w1, msg_b1, x, a0,
                                       nbr, ncnt, Fg, Wpack);
    for (int l = 0; l < L; l++) {
        float* a_cur  = (l & 1) ? a1 : a0;
        float* a_next = (l + 1 < L) ? ((l & 1) ? a0 : a1) : nullptr;
        const float* wxn = (l + 1 < L) ? (msg_w1 + (l + 1) * W1ROWS * H) : nullptr;
        const float* b1n = (l + 1 < L) ? (msg_b1 + (l + 1) * H) : nullptr;
        const int* oin  = (l == 0) ? nullptr : order_g;
        int*       oout = (l == 0) ? order_g : nullptr;
        k_layer<<<N, 512, 0, stream>>>(a_cur, nbr, ncnt, Fg, Wpack + l * 8192,
                                       msg_w2 + l * H * H, msg_b2 + l * H,
                                       upd_w1 + l * 2 * H * H, upd_b1 + l * H,
                                       upd_w2 + l * H * H, upd_b2 + l * H,
                                       x, wxn, b1n, a_next, oin, oout);
    }
    k_pool<<<NMOL, 512, 0, stream>>>(x, batch, out_w1, out_b1, out_w2, out_b2, out);
}